// Round 1
// baseline (548.174 us; speedup 1.0000x reference)
//
#include <hip/hip_runtime.h>

#define E_TOT   800000
#define NN      50000
#define FF      64

typedef __attribute__((ext_vector_type(8))) short  short8;
typedef __attribute__((ext_vector_type(4))) float  f32x4;

__device__ __forceinline__ unsigned short f2bf(float f) {
  union { float f; unsigned int u; } v; v.f = f;
  unsigned int r = v.u + 0x7fffu + ((v.u >> 16) & 1u);
  return (unsigned short)(r >> 16);
}

__device__ __forceinline__ float sigmoidf_(float x) {
  return 1.f / (1.f + __expf(-x));
}

// Pack W_mlpt|W_gate [192x64] f32 into MFMA B-fragment order bf16.
// slot t = ((m*4+nt)*6+kk)*64 + lane ; elems j=0..7 : W[kk*32+(lane>>4)*8+j][nt*16+(lane&15)]
__global__ void pack_w(const float* __restrict__ Wm, const float* __restrict__ Wg,
                       unsigned short* __restrict__ Wp) {
  int t = blockIdx.x * 256 + threadIdx.x;
  if (t >= 3072) return;
  int lane = t & 63;
  int kk   = (t >> 6) % 6;
  int mnt  = t / 384;            // 0..7
  const float* W = (mnt >> 2) ? Wg : Wm;
  int nt  = mnt & 3;
  int col = nt * 16 + (lane & 15);
  int kb  = kk * 32 + (lane >> 4) * 8;
  #pragma unroll
  for (int j = 0; j < 8; ++j)
    Wp[t * 8 + j] = f2bf(W[(kb + j) * 64 + col]);
}

// PASS 0: stats (col sums + sumsq of Y, 128 cols). PASS 1: BN+act+scatter.
template <int PASS>
__global__ __launch_bounds__(256, 2)
void edge_pass(const float* __restrict__ nodef, const float* __restrict__ edgef,
               const int* __restrict__ src, const int* __restrict__ dst,
               const unsigned short* __restrict__ Wp,
               float* __restrict__ stats,        // PASS0: 64 slots x 256
               const float* __restrict__ coef,   // PASS1: a[128], c[128]
               float* __restrict__ agg)          // PASS1: [NN*64] accumulator
{
  __shared__ unsigned short sh[64 * 200];
  __shared__ int sidx[64], didx[64];

  const int tid = threadIdx.x;
  const int e0  = blockIdx.x * 64;

  if (tid < 64)       sidx[tid]      = src[e0 + tid];
  else if (tid < 128) didx[tid - 64] = dst[e0 + tid - 64];
  __syncthreads();

  // stage h_cat tile [64 rows][192 cols] as bf16, row stride 200
  #pragma unroll
  for (int it = 0; it < 12; ++it) {
    int c    = tid + it * 256;       // 0..3071
    int row  = c / 48;
    int q    = c - row * 48;
    int part = q >> 4;               // 0=src,1=dst,2=edge
    int col4 = q & 15;
    const float* gp;
    if (part == 0)      gp = nodef + sidx[row] * 64 + col4 * 4;
    else if (part == 1) gp = nodef + didx[row] * 64 + col4 * 4;
    else                gp = edgef + (e0 + row) * 64 + col4 * 4;
    float4 v = *(const float4*)gp;
    ushort2 u01 = make_ushort2(f2bf(v.x), f2bf(v.y));
    ushort2 u23 = make_ushort2(f2bf(v.z), f2bf(v.w));
    unsigned short* sp = &sh[row * 200 + part * 64 + col4 * 4];
    *(ushort2*)(sp)     = u01;
    *(ushort2*)(sp + 2) = u23;
  }
  __syncthreads();

  const int w = tid >> 6, lane = tid & 63;
  f32x4 acc[8] = {};
  const unsigned short* abase = &sh[(w * 16 + (lane & 15)) * 200 + (lane >> 4) * 8];
  const short8* wp = (const short8*)Wp;

  #pragma unroll
  for (int kk = 0; kk < 6; ++kk) {
    short8 a = *(const short8*)(abase + kk * 32);
    #pragma unroll
    for (int nt = 0; nt < 8; ++nt) {
      short8 b = wp[(nt * 6 + kk) * 64 + lane];
      acc[nt] = __builtin_amdgcn_mfma_f32_16x16x32_bf16(a, b, acc[nt], 0, 0, 0);
    }
  }

  if constexpr (PASS == 0) {
    __shared__ float red[4 * 256];
    #pragma unroll
    for (int nt = 0; nt < 8; ++nt) {
      float s = acc[nt][0] + acc[nt][1] + acc[nt][2] + acc[nt][3];
      float q = acc[nt][0] * acc[nt][0] + acc[nt][1] * acc[nt][1] +
                acc[nt][2] * acc[nt][2] + acc[nt][3] * acc[nt][3];
      s += __shfl_xor(s, 16); s += __shfl_xor(s, 32);
      q += __shfl_xor(q, 16); q += __shfl_xor(q, 32);
      if ((lane >> 4) == 0) {
        red[w * 256 + nt * 16 + lane]       = s;
        red[w * 256 + 128 + nt * 16 + lane] = q;
      }
    }
    __syncthreads();
    float v = red[tid] + red[256 + tid] + red[512 + tid] + red[768 + tid];
    atomicAdd(&stats[(blockIdx.x & 63) * 256 + tid], v);
  } else {
    #pragma unroll
    for (int nt = 0; nt < 4; ++nt) {
      int col  = nt * 16 + (lane & 15);
      float am = coef[col],      cm = coef[128 + col];
      float ag = coef[64 + col], cg = coef[192 + col];
      #pragma unroll
      for (int r = 0; r < 4; ++r) {
        float ym  = acc[nt][r]     * am + cm;
        float yg  = acc[nt + 4][r] * ag + cg;
        float sig = sigmoidf_(ym);
        float sp  = (yg > 20.f) ? yg : log1pf(__expf(yg));
        int row   = w * 16 + (lane >> 4) * 4 + r;
        atomicAdd(&agg[didx[row] * 64 + col], sig * sp);
      }
    }
  }
}

__global__ void finalize_edge(const float* __restrict__ stats,
                              const float* __restrict__ g_m, const float* __restrict__ be_m,
                              const float* __restrict__ g_g, const float* __restrict__ be_g,
                              float* __restrict__ coef) {
  int c = threadIdx.x;  // 0..127
  float s = 0.f, q = 0.f;
  for (int sl = 0; sl < 64; ++sl) { s += stats[sl * 256 + c]; q += stats[sl * 256 + 128 + c]; }
  float mu  = s * (1.f / E_TOT);
  float var = fmaxf(q * (1.f / E_TOT) - mu * mu, 0.f);
  float g   = (c < 64) ? g_m[c]  : g_g[c - 64];
  float be  = (c < 64) ? be_m[c] : be_g[c - 64];
  float a   = g * rsqrtf(var + 1e-5f);
  coef[c]       = a;
  coef[128 + c] = be - mu * a;
}

__global__ void node_stats(const float* __restrict__ agg, float* __restrict__ nstats) {
  __shared__ float rs[256], rq[256];
  int tid = threadIdx.x;
  int col = tid & 63;
  float s = 0.f, q = 0.f;
  for (int r = blockIdx.x * 4 + (tid >> 6); r < NN; r += gridDim.x * 4) {
    float v = agg[r * 64 + col];
    s += v; q += v * v;
  }
  rs[tid] = s; rq[tid] = q;
  __syncthreads();
  if (tid < 64) {
    s = rs[tid] + rs[tid + 64] + rs[tid + 128] + rs[tid + 192];
    q = rq[tid] + rq[tid + 64] + rq[tid + 128] + rq[tid + 192];
    int slot = blockIdx.x & 31;
    atomicAdd(&nstats[slot * 128 + col], s);
    atomicAdd(&nstats[slot * 128 + 64 + col], q);
  }
}

__global__ void finalize_node(const float* __restrict__ nstats,
                              const float* __restrict__ g_n, const float* __restrict__ be_n,
                              float* __restrict__ coefn) {
  int c = threadIdx.x;  // 0..63
  float s = 0.f, q = 0.f;
  for (int sl = 0; sl < 32; ++sl) { s += nstats[sl * 128 + c]; q += nstats[sl * 128 + 64 + c]; }
  float mu  = s * (1.f / NN);
  float var = fmaxf(q * (1.f / NN) - mu * mu, 0.f);
  float a   = g_n[c] * rsqrtf(var + 1e-5f);
  coefn[c]      = a;
  coefn[64 + c] = be_n[c] - mu * a;
}

__global__ void node_out_k(float* __restrict__ out, const float* __restrict__ nodef,
                           const float* __restrict__ coefn) {
  int i  = blockIdx.x * 256 + threadIdx.x;   // one float4 per thread, 800000 total
  int cb = (i & 15) * 4;
  float4 a  = ((float4*)out)[i];
  float4 nf = ((const float4*)nodef)[i];
  float4 r;
  r.x = sigmoidf_(coefn[cb + 0] * a.x + coefn[64 + cb + 0] + nf.x);
  r.y = sigmoidf_(coefn[cb + 1] * a.y + coefn[64 + cb + 1] + nf.y);
  r.z = sigmoidf_(coefn[cb + 2] * a.z + coefn[64 + cb + 2] + nf.z);
  r.w = sigmoidf_(coefn[cb + 3] * a.w + coefn[64 + cb + 3] + nf.w);
  ((float4*)out)[i] = r;
}

extern "C" void kernel_launch(void* const* d_in, const int* in_sizes, int n_in,
                              void* d_out, int out_size, void* d_ws, size_t ws_size,
                              hipStream_t stream) {
  const float* nodef = (const float*)d_in[0];
  const float* edgef = (const float*)d_in[1];
  const int*   src   = (const int*)d_in[2];
  const int*   dst   = (const int*)d_in[3];
  const float* W_m   = (const float*)d_in[4];
  const float* g_m   = (const float*)d_in[6];
  const float* be_m  = (const float*)d_in[7];
  const float* W_g   = (const float*)d_in[8];
  const float* g_g   = (const float*)d_in[10];
  const float* be_g  = (const float*)d_in[11];
  const float* g_n   = (const float*)d_in[12];
  const float* be_n  = (const float*)d_in[13];

  float* out = (float*)d_out;
  char*  ws  = (char*)d_ws;
  float*          stats  = (float*)ws;             // 64 slots x 256 f32 = 65536 B
  float*          coef   = (float*)(ws + 65536);   // 256 f32
  float*          nstats = (float*)(ws + 66560);   // 32 slots x 128 f32 = 16384 B
  float*          coefn  = (float*)(ws + 82944);   // 128 f32
  unsigned short* Wp     = (unsigned short*)(ws + 83456); // 24576 bf16 = 49152 B

  // zero agg accumulator (node region of d_out) and stat slots
  hipMemsetAsync(d_out, 0, (size_t)NN * FF * sizeof(float), stream);
  hipMemsetAsync(d_ws, 0, 83456, stream);
  // output 2: verbatim edge_feats copy
  hipMemcpyAsync(out + (size_t)NN * FF, edgef, (size_t)E_TOT * FF * sizeof(float),
                 hipMemcpyDeviceToDevice, stream);

  pack_w<<<12, 256, 0, stream>>>(W_m, W_g, Wp);
  edge_pass<0><<<E_TOT / 64, 256, 0, stream>>>(nodef, edgef, src, dst, Wp, stats, nullptr, nullptr);
  finalize_edge<<<1, 128, 0, stream>>>(stats, g_m, be_m, g_g, be_g, coef);
  edge_pass<1><<<E_TOT / 64, 256, 0, stream>>>(nodef, edgef, src, dst, Wp, nullptr, coef, out);
  node_stats<<<512, 256, 0, stream>>>(out, nstats);
  finalize_node<<<1, 64, 0, stream>>>(nstats, g_n, be_n, coefn);
  node_out_k<<<NN * FF / 4 / 256, 256, 0, stream>>>(out, nodef, coefn);
}

// Round 2
// 444.286 us; speedup vs baseline: 1.2338x; 1.2338x over previous
//
#include <hip/hip_runtime.h>

#define E_TOT   800000
#define NN      50000
#define FF      64

typedef __attribute__((ext_vector_type(8))) short  short8;
typedef __attribute__((ext_vector_type(4))) float  f32x4;

__device__ __forceinline__ unsigned short f2bf(float f) {
  union { float f; unsigned int u; } v; v.f = f;
  unsigned int r = v.u + 0x7fffu + ((v.u >> 16) & 1u);
  return (unsigned short)(r >> 16);
}

// pack two f32 -> one u32 of 2 bf16 (RNE) in a single instruction
__device__ __forceinline__ unsigned int pkbf(float a, float b) {
  unsigned int r;
  asm("v_cvt_pk_bf16_f32 %0, %1, %2" : "=v"(r) : "v"(a), "v"(b));
  return r;
}

__device__ __forceinline__ float sigmoidf_(float x) {
  return 1.f / (1.f + __expf(-x));
}

// Pack W_mlpt|W_gate [192x64] f32 into MFMA B-fragment order bf16.
__global__ void pack_w(const float* __restrict__ Wm, const float* __restrict__ Wg,
                       unsigned short* __restrict__ Wp) {
  int t = blockIdx.x * 256 + threadIdx.x;
  if (t >= 3072) return;
  int lane = t & 63;
  int kk   = (t >> 6) % 6;
  int mnt  = t / 384;            // 0..7
  const float* W = (mnt >> 2) ? Wg : Wm;
  int nt  = mnt & 3;
  int col = nt * 16 + (lane & 15);
  int kb  = kk * 32 + (lane >> 4) * 8;
  #pragma unroll
  for (int j = 0; j < 8; ++j)
    Wp[t * 8 + j] = f2bf(W[(kb + j) * 64 + col]);
}

// Fused gather + bf16 convert + GEMM; emits col stats and Y (bf16, MFMA-reg layout).
__global__ __launch_bounds__(256)
void edge_gemm(const float* __restrict__ nodef, const float* __restrict__ edgef,
               const int* __restrict__ src, const int* __restrict__ dst,
               const unsigned short* __restrict__ Wp,
               float* __restrict__ stats,          // 64 slots x 256
               uint4* __restrict__ Yw)             // [12500*4*4*64] uint4
{
  __shared__ unsigned short sh[64 * 200];          // row stride 200 ushort = 400 B

  const int tid = threadIdx.x;
  const int e0  = blockIdx.x * 64;
  const int row = tid >> 2;                        // 0..63 (fixed per thread)
  const int cq  = tid & 3;                         // float4 lane within 16-float chunk

  const int s = src[e0 + row], d = dst[e0 + row];
  const float* ps = nodef + (size_t)s * 64 + cq * 4;
  const float* pd = nodef + (size_t)d * 64 + cq * 4;
  const float* pe = edgef + (size_t)(e0 + row) * 64 + cq * 4;
  unsigned short* sp = &sh[row * 200 + cq * 4];

  #pragma unroll
  for (int it = 0; it < 4; ++it) {
    float4 v0 = *(const float4*)(ps + it * 16);
    float4 v1 = *(const float4*)(pd + it * 16);
    float4 v2 = *(const float4*)(pe + it * 16);
    uint2 w0 = make_uint2(pkbf(v0.x, v0.y), pkbf(v0.z, v0.w));
    uint2 w1 = make_uint2(pkbf(v1.x, v1.y), pkbf(v1.z, v1.w));
    uint2 w2 = make_uint2(pkbf(v2.x, v2.y), pkbf(v2.z, v2.w));
    *(uint2*)(sp +   0 + it * 16) = w0;   // src  part: ushort off part*64
    *(uint2*)(sp +  64 + it * 16) = w1;   // dst  part
    *(uint2*)(sp + 128 + it * 16) = w2;   // edge part
  }
  __syncthreads();

  const int w = tid >> 6, lane = tid & 63;
  f32x4 acc[8] = {};
  const unsigned short* abase = &sh[(w * 16 + (lane & 15)) * 200 + (lane >> 4) * 8];
  const short8* wp = (const short8*)Wp;

  #pragma unroll
  for (int kk = 0; kk < 6; ++kk) {
    short8 a = *(const short8*)(abase + kk * 32);
    #pragma unroll
    for (int nt = 0; nt < 8; ++nt) {
      short8 b = wp[(nt * 6 + kk) * 64 + lane];
      acc[nt] = __builtin_amdgcn_mfma_f32_16x16x32_bf16(a, b, acc[nt], 0, 0, 0);
    }
  }

  // write Y as bf16 in MFMA-register layout (fully coalesced)
  uint4* yb = Yw + (((size_t)blockIdx.x * 4 + w) * 4) * 64 + lane;
  #pragma unroll
  for (int ntp = 0; ntp < 4; ++ntp) {
    uint4 q;
    q.x = pkbf(acc[2 * ntp][0],     acc[2 * ntp][1]);
    q.y = pkbf(acc[2 * ntp][2],     acc[2 * ntp][3]);
    q.z = pkbf(acc[2 * ntp + 1][0], acc[2 * ntp + 1][1]);
    q.w = pkbf(acc[2 * ntp + 1][2], acc[2 * ntp + 1][3]);
    yb[ntp * 64] = q;
  }

  // column sums / sumsq reduction
  __shared__ float red[4 * 256];
  #pragma unroll
  for (int nt = 0; nt < 8; ++nt) {
    float sv = acc[nt][0] + acc[nt][1] + acc[nt][2] + acc[nt][3];
    float qv = acc[nt][0] * acc[nt][0] + acc[nt][1] * acc[nt][1] +
               acc[nt][2] * acc[nt][2] + acc[nt][3] * acc[nt][3];
    sv += __shfl_xor(sv, 16); sv += __shfl_xor(sv, 32);
    qv += __shfl_xor(qv, 16); qv += __shfl_xor(qv, 32);
    if ((lane >> 4) == 0) {
      red[w * 256 + nt * 16 + lane]       = sv;
      red[w * 256 + 128 + nt * 16 + lane] = qv;
    }
  }
  __syncthreads();
  float v = red[tid] + red[256 + tid] + red[512 + tid] + red[768 + tid];
  atomicAdd(&stats[(blockIdx.x & 63) * 256 + tid], v);
}

// Read Y (bf16 reg layout), apply folded BN + activations, scatter-add to agg.
__global__ __launch_bounds__(256)
void edge_apply(const uint4* __restrict__ Yw, const int* __restrict__ dst,
                const float* __restrict__ coef,  // a[128], c[128]
                float* __restrict__ agg)
{
  const int tid = threadIdx.x;
  const int w = tid >> 6, lane = tid & 63;
  const int e0 = blockIdx.x * 64;
  const int r0 = w * 16 + ((lane >> 4) << 2);
  const int4 dn = *(const int4*)&dst[e0 + r0];
  const int colb = lane & 15;

  const uint4* yb = Yw + (((size_t)blockIdx.x * 4 + w) * 4) * 64 + lane;
  uint4 qm0 = yb[0], qm1 = yb[64], qg0 = yb[128], qg1 = yb[192];
  const unsigned int um[8] = {qm0.x, qm0.y, qm0.z, qm0.w, qm1.x, qm1.y, qm1.z, qm1.w};
  const unsigned int ug[8] = {qg0.x, qg0.y, qg0.z, qg0.w, qg1.x, qg1.y, qg1.z, qg1.w};

  const int dr[4] = {dn.x, dn.y, dn.z, dn.w};

  #pragma unroll
  for (int ntm = 0; ntm < 4; ++ntm) {
    const int col = ntm * 16 + colb;
    const float am = coef[col],      cm = coef[128 + col];
    const float ag = coef[64 + col], cg = coef[192 + col];
    #pragma unroll
    for (int p = 0; p < 2; ++p) {            // p: pair of rows (r = 2p, 2p+1)
      unsigned int m = um[ntm * 2 + p], g = ug[ntm * 2 + p];
      #pragma unroll
      for (int h = 0; h < 2; ++h) {          // h: lo/hi half of the packed u32
        float mv = __uint_as_float(h ? (m & 0xffff0000u) : (m << 16));
        float gv = __uint_as_float(h ? (g & 0xffff0000u) : (g << 16));
        float ym = fmaf(mv, am, cm);
        float yg = fmaf(gv, ag, cg);
        float sig = sigmoidf_(ym);
        float sp  = (yg > 20.f) ? yg : __logf(1.f + __expf(yg));
        int r = 2 * p + h;
        atomicAdd(&agg[(size_t)dr[r] * 64 + col], sig * sp);
      }
    }
  }
}

__global__ void finalize_edge(const float* __restrict__ stats,
                              const float* __restrict__ g_m, const float* __restrict__ be_m,
                              const float* __restrict__ g_g, const float* __restrict__ be_g,
                              float* __restrict__ coef) {
  int c = threadIdx.x;  // 0..127
  float s = 0.f, q = 0.f;
  for (int sl = 0; sl < 64; ++sl) { s += stats[sl * 256 + c]; q += stats[sl * 256 + 128 + c]; }
  float mu  = s * (1.f / E_TOT);
  float var = fmaxf(q * (1.f / E_TOT) - mu * mu, 0.f);
  float g   = (c < 64) ? g_m[c]  : g_g[c - 64];
  float be  = (c < 64) ? be_m[c] : be_g[c - 64];
  float a   = g * rsqrtf(var + 1e-5f);
  coef[c]       = a;
  coef[128 + c] = be - mu * a;
}

__global__ void node_stats(const float* __restrict__ agg, float* __restrict__ nstats) {
  __shared__ float rs[256], rq[256];
  int tid = threadIdx.x;
  int col = tid & 63;
  float s = 0.f, q = 0.f;
  for (int r = blockIdx.x * 4 + (tid >> 6); r < NN; r += gridDim.x * 4) {
    float v = agg[r * 64 + col];
    s += v; q += v * v;
  }
  rs[tid] = s; rq[tid] = q;
  __syncthreads();
  if (tid < 64) {
    s = rs[tid] + rs[tid + 64] + rs[tid + 128] + rs[tid + 192];
    q = rq[tid] + rq[tid + 64] + rq[tid + 128] + rq[tid + 192];
    int slot = blockIdx.x & 31;
    atomicAdd(&nstats[slot * 128 + col], s);
    atomicAdd(&nstats[slot * 128 + 64 + col], q);
  }
}

__global__ void finalize_node(const float* __restrict__ nstats,
                              const float* __restrict__ g_n, const float* __restrict__ be_n,
                              float* __restrict__ coefn) {
  int c = threadIdx.x;  // 0..63
  float s = 0.f, q = 0.f;
  for (int sl = 0; sl < 32; ++sl) { s += nstats[sl * 128 + c]; q += nstats[sl * 128 + 64 + c]; }
  float mu  = s * (1.f / NN);
  float var = fmaxf(q * (1.f / NN) - mu * mu, 0.f);
  float a   = g_n[c] * rsqrtf(var + 1e-5f);
  coefn[c]      = a;
  coefn[64 + c] = be_n[c] - mu * a;
}

__global__ void node_out_k(float* __restrict__ out, const float* __restrict__ nodef,
                           const float* __restrict__ coefn) {
  int i  = blockIdx.x * 256 + threadIdx.x;   // one float4 per thread, 800000 total
  int cb = (i & 15) * 4;
  float4 a  = ((float4*)out)[i];
  float4 nf = ((const float4*)nodef)[i];
  float4 r;
  r.x = sigmoidf_(coefn[cb + 0] * a.x + coefn[64 + cb + 0] + nf.x);
  r.y = sigmoidf_(coefn[cb + 1] * a.y + coefn[64 + cb + 1] + nf.y);
  r.z = sigmoidf_(coefn[cb + 2] * a.z + coefn[64 + cb + 2] + nf.z);
  r.w = sigmoidf_(coefn[cb + 3] * a.w + coefn[64 + cb + 3] + nf.w);
  ((float4*)out)[i] = r;
}

extern "C" void kernel_launch(void* const* d_in, const int* in_sizes, int n_in,
                              void* d_out, int out_size, void* d_ws, size_t ws_size,
                              hipStream_t stream) {
  const float* nodef = (const float*)d_in[0];
  const float* edgef = (const float*)d_in[1];
  const int*   src   = (const int*)d_in[2];
  const int*   dst   = (const int*)d_in[3];
  const float* W_m   = (const float*)d_in[4];
  const float* g_m   = (const float*)d_in[6];
  const float* be_m  = (const float*)d_in[7];
  const float* W_g   = (const float*)d_in[8];
  const float* g_g   = (const float*)d_in[10];
  const float* be_g  = (const float*)d_in[11];
  const float* g_n   = (const float*)d_in[12];
  const float* be_n  = (const float*)d_in[13];

  float* out = (float*)d_out;
  float* agg = out;                                   // [NN*64] node accumulator
  uint4* Yw  = (uint4*)(out + (size_t)NN * FF);       // Y bf16 lives in edge region until copy

  char*  ws  = (char*)d_ws;
  float*          stats  = (float*)ws;             // 64 slots x 256 f32 = 65536 B
  float*          coef   = (float*)(ws + 65536);   // 256 f32
  float*          nstats = (float*)(ws + 66560);   // 32 slots x 128 f32 = 16384 B
  float*          coefn  = (float*)(ws + 82944);   // 128 f32
  unsigned short* Wp     = (unsigned short*)(ws + 83456); // 24576 bf16

  hipMemsetAsync(agg, 0, (size_t)NN * FF * sizeof(float), stream);
  hipMemsetAsync(d_ws, 0, 83456, stream);

  pack_w<<<12, 256, 0, stream>>>(W_m, W_g, Wp);
  edge_gemm<<<E_TOT / 64, 256, 0, stream>>>(nodef, edgef, src, dst, Wp, stats, Yw);
  finalize_edge<<<1, 128, 0, stream>>>(stats, g_m, be_m, g_g, be_g, coef);
  edge_apply<<<E_TOT / 64, 256, 0, stream>>>(Yw, dst, coef, agg);
  // edge output: verbatim copy (overwrites Y region only after edge_apply finished)
  hipMemcpyAsync(out + (size_t)NN * FF, edgef, (size_t)E_TOT * FF * sizeof(float),
                 hipMemcpyDeviceToDevice, stream);
  node_stats<<<512, 256, 0, stream>>>(agg, nstats);
  finalize_node<<<1, 64, 0, stream>>>(nstats, g_n, be_n, coefn);
  node_out_k<<<NN * FF / 4 / 256, 256, 0, stream>>>(agg, nodef, coefn);
}